// Round 8
// baseline (1179.484 us; speedup 1.0000x reference)
//
#include <hip/hip_runtime.h>
#include <hip/hip_bf16.h>

// ---- problem dims (fixed) ----
#define NCLS 4
#define BS   16
#define NT   32
#define OC   12
#define HW   4096
#define PIX  65536
#define STATE 786432        // PIX*OC
#define BANK  3145728       // NCLS*STATE

typedef short bf16x8 __attribute__((ext_vector_type(8)));
typedef float f32x4  __attribute__((ext_vector_type(4)));

// jax.nn.hard_sigmoid = relu6(x+3)/6
__device__ __forceinline__ float hsig(float v){
    return fminf(fmaxf((v + 3.0f) * (1.0f/6.0f), 0.0f), 1.0f);
}
__device__ __forceinline__ short f2bf(float f){
    union { __hip_bfloat16 h; short s; } u;
    u.h = __float2bfloat16(f);   // RNE
    return u.s;
}

// =====================================================================
// Weight repack: fragment-order bf16.
// wgt[cell][tap][kb][nt][lane], elem j = B[k=kb*32+(lane>>4)*8+j][n=nt*16+(lane&15)]
// gen  k-order (unchanged, verified): bank48 | genh12 | 0
// class k-order (NEW):               frame12 | clsh12 | genh12 | 0
// =====================================================================
__global__ __launch_bounds__(256) void repack_kernel(
    const float* __restrict__ Wxg, const float* __restrict__ Whg,
    const float* __restrict__ Wxc, const float* __restrict__ Whc,
    bf16x8* __restrict__ wgt)
{
    int id = blockIdx.x * 256 + threadIdx.x;    // < 6912
    if (id >= 6912) return;
    int cell = id / 3456;
    int rem  = id - cell * 3456;
    int tap  = rem / 384;  rem -= tap * 384;
    int kb   = rem / 192;  rem -= kb * 192;
    int nt   = rem / 64;
    int lane = rem - nt * 64;
    int quad = lane >> 4;
    int n    = nt * 16 + (lane & 15);
    union { bf16x8 v; short s[8]; } o;
    #pragma unroll
    for (int j = 0; j < 8; ++j){
        int k = kb * 32 + quad * 8 + j;
        float f = 0.0f;
        if (cell == 0){
            if (k < 48)      f = Wxg[(tap*48 + k)*48 + n];
            else if (k < 60) f = Whg[(tap*12 + (k-48))*48 + n];
        } else {
            if (k < 12)      f = Wxc[(tap*24 + k)*48 + n];            // frame
            else if (k < 24) f = Whc[(tap*12 + (k-12))*48 + n];       // class_h
            else if (k < 36) f = Wxc[(tap*24 + 12 + (k-24))*48 + n];  // gen_h
        }
        o.s[j] = f2bf(f);
    }
    wgt[id] = o.v;
}

// =====================================================================
// Fused per-step kernel. 256 blocks x 256 thr, 1 block/CU (LDS 63.4 KB).
// Block owns 4 class rows (y0..y0+3) of image b; computes gen for rows
// y0-1..y0+4 (2 redundant halo rows, bit-identical to neighbors').
// LDS: ghalo = gen 3-row halo (per row-pass) + z overlay; creg = class
// A-operand planes [plane][hrow6][hcol66][8ch]:
//   p0 frame0-7 | p1 frame8-11+clsh0-3 | p2 clsh4-11 | p3 genh0-7
//   p4 genh8-11+0 | p5 zero (kb1 quads 1-3)
// =====================================================================
#define GH_SHORTS (8*198*8)       // 25344 B
#define CREG_SHORTS (6*6*66*8)    // 38016 B

__global__ __launch_bounds__(256, 1) void fused_kernel(
    short* __restrict__ bank,            // (PIX*48) bf16 flat
    const short* __restrict__ hin,       // (PIX,12) bf16  gen_h in
    short* __restrict__ hnew,            // (PIX,12) bf16  gen_h out
    const float* __restrict__ genc_in,   // (PIX,12) f32
    float* __restrict__ genc_out,        // (PIX,12) f32
    const short* __restrict__ htmp_prev, // (PIX,12) bf16
    short* __restrict__ htmp_new,        // (PIX,12) bf16
    const float* __restrict__ xall,      // (BS,NT,HW,12) f32
    const int* __restrict__ ids, int t,
    const bf16x8* __restrict__ wgt_gen,
    const bf16x8* __restrict__ wgt_cls,
    const float* __restrict__ bias_g,
    const float* __restrict__ bias_c,
    float* __restrict__ class_c,         // (NCLS,PIX,12) f32
    float* __restrict__ out)             // (PIX,12) f32 accum
{
    __shared__ __align__(16) short ghalo[GH_SHORTS];
    __shared__ __align__(16) short creg[CREG_SHORTS];

    const int tid  = threadIdx.x;
    const int lane = tid & 63;
    const int w    = tid >> 6;
    const int m    = lane & 15;
    const int quad = lane >> 4;
    const int colbase = 16*w + m;

    // XCD swizzle: XCD j = blockIdx&7 gets 4-row groups [32j,32j+32) = 2 images
    const int g  = ((blockIdx.x & 7) << 5) | (blockIdx.x >> 3);
    const int b  = g >> 4;
    const int y0 = (g & 15) * 4;

    const int cid   = ids[t];
    const int cprev = (t > 0) ? ids[t-1] : -1;
    const bool slotmatch = (cprev >= 0) && ((b >> 2) == cprev);
    const short* bsrc = slotmatch ? htmp_prev : bank;

    // zero creg planes 3..5 (genh planes + kb1 zero plane)
    for (int i = tid; i < 1188; i += 256)
        *(uint4*)&creg[(1188 + i)*8] = make_uint4(0u,0u,0u,0u);

    // ================= gen phase: 6 row-passes =================
    for (int pass = 0; pass < 6; ++pass){
        const int yy = y0 - 1 + pass;
        if (yy < 0 || yy > 63) continue;            // block-uniform
        const bool ownedrow = (pass >= 1) && (pass <= 4);

        // ---- stage 3-row halo (verified R6 structure) ----
        {
            const int i = tid;
            const bool active = (i < 198);
            int r  = i / 66, c = i - r * 66;
            int ry = yy + r - 1, xx = c - 1;
            bool valid = active & (ry >= 0) & (ry < 64) & (xx >= 0) & (xx < 64);
            int p  = (b << 12) + (ry << 6) + xx;
            int pb = slotmatch ? (p & 16383) : p;
            uint4 bk[6]; uint2 h0, h1, h2;
            #pragma unroll
            for (int q = 0; q < 6; ++q) bk[q] = make_uint4(0u,0u,0u,0u);
            h0 = make_uint2(0u,0u); h1 = h0; h2 = h0;
            if (valid){
                const short* bp = bsrc + pb*48;
                #pragma unroll
                for (int q = 0; q < 6; ++q) bk[q] = *(const uint4*)(bp + q*8);
                h0 = *(const uint2*)(hin + p*12);
                h1 = *(const uint2*)(hin + p*12 + 4);
                h2 = *(const uint2*)(hin + p*12 + 8);
                if (slotmatch && r == 1 && ownedrow){   // refresh bank once/owned row
                    #pragma unroll
                    for (int q = 0; q < 6; ++q)
                        *(uint4*)(bank + p*48 + q*8) = bk[q];
                }
            }
            if (active){
                #pragma unroll
                for (int q = 0; q < 6; ++q)
                    *(uint4*)&ghalo[(q*198 + i)*8] = bk[q];
                union { uint2 u2[2]; uint4 u4; } p6, p7;
                p6.u2[0] = h0; p6.u2[1] = h1;
                p7.u2[0] = h2; p7.u2[1] = make_uint2(0u,0u);
                *(uint4*)&ghalo[(6*198 + i)*8] = p6.u4;
                *(uint4*)&ghalo[(7*198 + i)*8] = p7.u4;
            }
        }
        __syncthreads();

        // ---- 54 MFMA ----
        f32x4 acc0 = {0.f,0.f,0.f,0.f};
        f32x4 acc1 = acc0, acc2 = acc0;
        #pragma unroll
        for (int ky = 0; ky < 3; ++ky){
            #pragma unroll
            for (int kx = 0; kx < 3; ++kx){
                const int tap = ky*3 + kx;
                #pragma unroll
                for (int kb = 0; kb < 2; ++kb){
                    const bf16x8 a = *(const bf16x8*)
                        &ghalo[(((kb*4 + quad)*198) + ky*66 + colbase + kx)*8];
                    const bf16x8* wp = wgt_gen + ((tap*2 + kb)*3)*64 + lane;
                    acc0 = __builtin_amdgcn_mfma_f32_16x16x32_bf16(a, wp[0],   acc0, 0,0,0);
                    acc1 = __builtin_amdgcn_mfma_f32_16x16x32_bf16(a, wp[64],  acc1, 0,0,0);
                    acc2 = __builtin_amdgcn_mfma_f32_16x16x32_bf16(a, wp[128], acc2, 0,0,0);
                }
            }
        }
        __syncthreads();

        // ---- z transpose (own-wave region in ghalo) + epilogue ----
        float* zw = ((float*)ghalo) + w * 768;
        #pragma unroll
        for (int r2 = 0; r2 < 4; ++r2){
            zw[(quad*4 + r2)*48 +      m] = acc0[r2];
            zw[(quad*4 + r2)*48 + 16 + m] = acc1[r2];
            zw[(quad*4 + r2)*48 + 32 + m] = acc2[r2];
        }
        const int pbase = (b << 12) + (yy << 6) + 16*w;
        #pragma unroll
        for (int s = 0; s < 3; ++s){
            int idx = lane*3 + s;
            int px  = idx / 12;
            int j   = idx - px*12;
            float zi = zw[px*48 +      j] + bias_g[j];
            float zf = zw[px*48 + 12 + j] + bias_g[12 + j];
            float zg = zw[px*48 + 24 + j] + bias_g[24 + j];
            float zo = zw[px*48 + 36 + j] + bias_g[36 + j];
            int off = pbase*12 + idx;
            float cn = hsig(zf)*genc_in[off] + hsig(zi)*tanhf(zg);
            float h  = hsig(zo)*tanhf(cn);
            short hb = f2bf(h);
            if (ownedrow){
                genc_out[off] = cn;
                hnew[off] = hb;
            }
            // gen_h -> class planes: k = 24+j
            int plane = 3 + (j >> 3), slot = j & 7, hcol = px + 16*w + 1;
            creg[((plane*6 + pass)*66 + hcol)*8 + slot] = hb;
        }
        __syncthreads();
    }

    // ================= class staging (planes 0..2) =================
    {
        const short* chs = (cid == cprev) ? htmp_prev
                                          : (bank + (size_t)cid * STATE);
        const float* frame = xall + (size_t)(b*NT + t) * (HW*12);
        for (int i = tid; i < 396; i += 256){
            int hr = i / 66, c = i - hr*66;
            int ry = y0 - 1 + hr, xx = c - 1;
            bool valid = (ry >= 0) & (ry < 64) & (xx >= 0) & (xx < 64);
            int pl = (ry << 6) + xx;
            int p  = (b << 12) + pl;
            float4 f0 = make_float4(0.f,0.f,0.f,0.f), f1 = f0, f2 = f0;
            uint2 u0 = make_uint2(0u,0u), u1 = u0, u2 = u0;
            if (valid){
                f0 = *(const float4*)(frame + pl*12);
                f1 = *(const float4*)(frame + pl*12 + 4);
                f2 = *(const float4*)(frame + pl*12 + 8);
                u0 = *(const uint2*)(chs + p*12);
                u1 = *(const uint2*)(chs + p*12 + 4);
                u2 = *(const uint2*)(chs + p*12 + 8);
            }
            union { uint4 u4; uint2 u2s[2]; short s[8]; } pk;
            pk.s[0]=f2bf(f0.x); pk.s[1]=f2bf(f0.y); pk.s[2]=f2bf(f0.z); pk.s[3]=f2bf(f0.w);
            pk.s[4]=f2bf(f1.x); pk.s[5]=f2bf(f1.y); pk.s[6]=f2bf(f1.z); pk.s[7]=f2bf(f1.w);
            *(uint4*)&creg[((0*6 + hr)*66 + c)*8] = pk.u4;
            pk.s[0]=f2bf(f2.x); pk.s[1]=f2bf(f2.y); pk.s[2]=f2bf(f2.z); pk.s[3]=f2bf(f2.w);
            pk.u2s[1] = u0;
            *(uint4*)&creg[((1*6 + hr)*66 + c)*8] = pk.u4;
            pk.u2s[0] = u1; pk.u2s[1] = u2;
            *(uint4*)&creg[((2*6 + hr)*66 + c)*8] = pk.u4;
        }
    }
    __syncthreads();

    // ================= class: 4 owned rows =================
    float* cc = class_c + (size_t)cid * STATE;
    const int kb1plane = (quad == 0) ? 4 : 5;
    for (int rr = 0; rr < 4; ++rr){
        f32x4 acc0 = {0.f,0.f,0.f,0.f};
        f32x4 acc1 = acc0, acc2 = acc0;
        #pragma unroll
        for (int ky = 0; ky < 3; ++ky){
            #pragma unroll
            for (int kx = 0; kx < 3; ++kx){
                const int tap = ky*3 + kx;
                const int hr  = rr + ky;
                const bf16x8 a0 = *(const bf16x8*)
                    &creg[((quad*6 + hr)*66 + colbase + kx)*8];
                const bf16x8* wp0 = wgt_cls + ((tap*2 + 0)*3)*64 + lane;
                acc0 = __builtin_amdgcn_mfma_f32_16x16x32_bf16(a0, wp0[0],   acc0, 0,0,0);
                acc1 = __builtin_amdgcn_mfma_f32_16x16x32_bf16(a0, wp0[64],  acc1, 0,0,0);
                acc2 = __builtin_amdgcn_mfma_f32_16x16x32_bf16(a0, wp0[128], acc2, 0,0,0);
                const bf16x8 a1 = *(const bf16x8*)
                    &creg[((kb1plane*6 + hr)*66 + colbase + kx)*8];
                const bf16x8* wp1 = wgt_cls + ((tap*2 + 1)*3)*64 + lane;
                acc0 = __builtin_amdgcn_mfma_f32_16x16x32_bf16(a1, wp1[0],   acc0, 0,0,0);
                acc1 = __builtin_amdgcn_mfma_f32_16x16x32_bf16(a1, wp1[64],  acc1, 0,0,0);
                acc2 = __builtin_amdgcn_mfma_f32_16x16x32_bf16(a1, wp1[128], acc2, 0,0,0);
            }
        }
        float* zw = ((float*)ghalo) + w * 768;     // ghalo free now; own-wave
        #pragma unroll
        for (int r2 = 0; r2 < 4; ++r2){
            zw[(quad*4 + r2)*48 +      m] = acc0[r2];
            zw[(quad*4 + r2)*48 + 16 + m] = acc1[r2];
            zw[(quad*4 + r2)*48 + 32 + m] = acc2[r2];
        }
        const int pbase = (b << 12) + ((y0 + rr) << 6) + 16*w;
        #pragma unroll
        for (int s = 0; s < 3; ++s){
            int idx = lane*3 + s;
            int px  = idx / 12;
            int j   = idx - px*12;
            float zi = zw[px*48 +      j] + bias_c[j];
            float zf = zw[px*48 + 12 + j] + bias_c[12 + j];
            float zg = zw[px*48 + 24 + j] + bias_c[24 + j];
            float zo = zw[px*48 + 36 + j] + bias_c[36 + j];
            int off = pbase*12 + idx;
            float cn = hsig(zf)*cc[off] + hsig(zi)*tanhf(zg);
            cc[off] = cn;
            float h = hsig(zo)*tanhf(cn);
            htmp_new[off] = f2bf(h);
            out[off] += h;
        }
        __syncthreads();   // zw safe across rows (cheap; protects nothing else)
    }
}

extern "C" void kernel_launch(void* const* d_in, const int* in_sizes, int n_in,
                              void* d_out, int out_size, void* d_ws, size_t ws_size,
                              hipStream_t stream)
{
    (void)in_sizes; (void)n_in; (void)out_size; (void)ws_size;
    const float* x    = (const float*)d_in[0];
    const int*   ids  = (const int*)  d_in[1];
    const float* Wxg  = (const float*)d_in[2];
    const float* Whg  = (const float*)d_in[3];
    const float* bg   = (const float*)d_in[4];
    const float* Wxc  = (const float*)d_in[5];
    const float* Whc  = (const float*)d_in[6];
    const float* bc   = (const float*)d_in[7];
    float* out = (float*)d_out;

    char* base = (char*)d_ws;
    // zero region (one memset): bank | class_c | genc0 | genh0
    short*  bank    = (short*) (base);               //  6,291,456
    float*  class_c = (float*) (base +  6291456);    // 12,582,912
    float*  genc0   = (float*) (base + 18874368);    //  3,145,728
    short*  genh0   = (short*) (base + 22020096);    //  1,572,864  (zero end 23592960)
    float*  genc1   = (float*) (base + 23592960);    //  3,145,728
    short*  genh1   = (short*) (base + 26738688);    //  1,572,864
    short*  htmp0   = (short*) (base + 28311552);    //  1,572,864
    short*  htmp1   = (short*) (base + 29884416);    //  1,572,864
    bf16x8* wgt     = (bf16x8*)(base + 31457280);    //    110,592
    const bf16x8* wgt_gen = wgt;
    const bf16x8* wgt_cls = wgt + 3456;

    hipMemsetAsync(base, 0, (size_t)23592960, stream);
    hipMemsetAsync(out,  0, (size_t)4*STATE,  stream);

    repack_kernel<<<27, 256, 0, stream>>>(Wxg, Whg, Wxc, Whc, wgt);

    for (int t = 0; t < NT; ++t){
        const short* hi = (t & 1) ? genh1 : genh0;
        short*       hn = (t & 1) ? genh0 : genh1;
        const float* gi = (t & 1) ? genc1 : genc0;
        float*       go = (t & 1) ? genc0 : genc1;
        const short* hp = (t & 1) ? htmp0 : htmp1;
        short*       hw2= (t & 1) ? htmp1 : htmp0;
        fused_kernel<<<256, 256, 0, stream>>>(bank, hi, hn, gi, go, hp, hw2,
                                              x, ids, t, wgt_gen, wgt_cls,
                                              bg, bc, class_c, out);
    }
}